// Round 1
// baseline (86.266 us; speedup 1.0000x reference)
//
#include <hip/hip_runtime.h>
#include <math.h>

#define D 512
#define TEMP_INV 14.285714285714286f  // 1/0.07
#define NBT 16                         // 4096 / 256 tile grid dim
#define NBLK (NBT * (NBT + 1) / 2)     // 136 upper-tri tiles
#define NPAIRS 2048

typedef int v8i __attribute__((ext_vector_type(8)));
typedef float f32x16 __attribute__((ext_vector_type(16)));

// global->LDS direct DMA, 16 B per lane. LDS dest = wave-uniform base + lane*16.
#define GLDS16(g, l) __builtin_amdgcn_global_load_lds(                         \
    (const __attribute__((address_space(1))) unsigned int*)(g),                \
    (__attribute__((address_space(3))) unsigned int*)(l), 16, 0, 0)

// ws layout (float units):
//   [0]                neg_sum accumulator (float atomic)
//   [1]                block-completion counter (u32, last-block loss tail)
//   [64 .. 2112)       p values (positive-pair logits)
//   [2560 .. 18944)    scales: e8m0 byte per (row, 32-block) [4096][16] (64 KB)
//   [20480 .. 86016)   efp4: normalized fp4(e2m1) matrix [4096][256 B] (1 MB)

// fp4 e2m1 code for |x| (grid 0,.5,1,1.5,2,3,4,6), RNE-ish thresholds.
__device__ __forceinline__ unsigned fp4_code(float x) {
    const unsigned sg = (__float_as_uint(x) >> 31) << 3;
    const float u = fabsf(x);
    unsigned c = u < 0.25f ? 0u : u < 0.75f ? 1u : u < 1.25f ? 2u :
                 u < 1.75f ? 3u : u < 2.5f  ? 4u : u < 3.5f  ? 5u :
                 u < 5.0f  ? 6u : 7u;
    return c | sg;
}

// One wave per row: rsqrt(sum sq), per-32-block max -> e8m0 scale, fp4 encode.
__global__ void infonce_norm_cast_kernel(const float* __restrict__ emb,
                                         float* __restrict__ ws, int nrows) {
    if (blockIdx.x == 0 && threadIdx.x == 0) {
        ws[0] = 0.0f;                    // zero neg_sum
        ((unsigned int*)ws)[1] = 0u;     // zero completion counter
    }
    unsigned char* __restrict__ scales = (unsigned char*)(ws + 2560);
    unsigned char* __restrict__ efp4 = (unsigned char*)(ws + 20480);
    const int lane = threadIdx.x & 63;
    const int wave = threadIdx.x >> 6;
    const int row = blockIdx.x * 4 + wave;
    if (row >= nrows) return;
    const float* r = emb + (size_t)row * D;
    float4 v1 = *(const float4*)&r[lane * 4];          // elems lane*4..+3
    float4 v2 = *(const float4*)&r[256 + lane * 4];    // elems 256+lane*4..+3
    float s = v1.x * v1.x + v1.y * v1.y + v1.z * v1.z + v1.w * v1.w
            + v2.x * v2.x + v2.y * v2.y + v2.z * v2.z + v2.w * v2.w;
    #pragma unroll
    for (int off = 32; off > 0; off >>= 1) s += __shfl_down(s, off, 64);
    const float rn = __shfl(rsqrtf(s), 0, 64);

    float f1[4] = {v1.x * rn, v1.y * rn, v1.z * rn, v1.w * rn};
    float f2[4] = {v2.x * rn, v2.y * rn, v2.z * rn, v2.w * rn};
    float m1 = fmaxf(fmaxf(fabsf(f1[0]), fabsf(f1[1])),
                     fmaxf(fabsf(f1[2]), fabsf(f1[3])));
    float m2 = fmaxf(fmaxf(fabsf(f2[0]), fabsf(f2[1])),
                     fmaxf(fabsf(f2[2]), fabsf(f2[3])));
    // 32-block = 8 consecutive lanes' quads; block1 = lane>>3, block2 = 8+that
    #pragma unroll
    for (int o = 1; o < 8; o <<= 1) {
        m1 = fmaxf(m1, __shfl_xor(m1, o, 64));
        m2 = fmaxf(m2, __shfl_xor(m2, o, 64));
    }
    int e1, e2;
    (void)frexpf(m1, &e1);  // m1 = f*2^e1, f in [0.5,1)
    (void)frexpf(m2, &e2);
    const int s1 = e1 - 2, s2 = e2 - 2;  // scaled max in [2,4) <= 6
    const float inv1 = ldexpf(1.0f, -s1), inv2 = ldexpf(1.0f, -s2);

    unsigned h1 = 0, h2 = 0;
    #pragma unroll
    for (int j = 0; j < 4; ++j) {
        h1 |= fp4_code(f1[j] * inv1) << (4 * j);
        h2 |= fp4_code(f2[j] * inv2) << (4 * j);
    }
    unsigned short* rp = (unsigned short*)(efp4 + (size_t)row * 256);
    rp[lane] = (unsigned short)h1;        // bytes [lane*2, +2)
    rp[64 + lane] = (unsigned short)h2;   // bytes [128 + lane*2, +2)
    if ((lane & 7) == 0) {
        scales[(size_t)row * 16 + (lane >> 3)] = (unsigned char)(127 + s1);
        scales[(size_t)row * 16 + 8 + (lane >> 3)] = (unsigned char)(127 + s2);
    }
}

// Upper-triangular 256x256 tiles (136 blocks, 1/CU: A+B = 128 KB LDS), 512
// threads (8 waves). fp4 panels (256 x 256 B = 64 KB each), single-shot
// staging (16 glds/wave, ONE vmcnt drain at ONE barrier). Wave w -> 64x128
// output slab (wr=w>>1, wc=w&1): 2x4 acc tiles of 32x32, 64 mfma_scale with
// per-32-block e8m0 scales (fmt=4). Same XOR swizzle: 16 B chunk c of row r
// at slot c ^ (r&7).
// R15: loss kernel fused as last-block tail (device-scope counter at ws[1],
// release = syncthreads-drained stores + t0 __threadfence before the counter
// add; acquire = __threadfence + agent-scope atomic loads in the last block).
// Epilogue loop order (reg outer, nb inner) cuts label LDS reads 256->36 per
// lane; wave-uniform diag flag skips pair-store checks on off-diag blocks.
__global__ __launch_bounds__(512, 1) void infonce_sim_kernel(
        const int* __restrict__ labels, float* __restrict__ ws,
        float* __restrict__ out) {
    // contiguous-per-XCD chunking (136 % 8 == 0)
    const int grp = gridDim.x >> 3;  // 17
    const int tile = (blockIdx.x & 7) * grp + (blockIdx.x >> 3);
    // triangular decode: row-major over {(bi,bj): bj>=bi}
    int rem = tile, bi = 0;
    while (rem >= (NBT - bi)) { rem -= (NBT - bi); ++bi; }
    const int bj = bi + rem;

    const unsigned char* __restrict__ scales = (const unsigned char*)(ws + 2560);
    const unsigned char* __restrict__ efp4 = (const unsigned char*)(ws + 20480);
    float* __restrict__ pvals = ws + 64;

    __shared__ __align__(16) unsigned char As[256 * 256];  // 64 KB
    __shared__ __align__(16) unsigned char Bs[256 * 256];  // 64 KB
    __shared__ int lab_row[256], lab_col[256];
    __shared__ float red[8];
    __shared__ int lastflag;

    const int t = threadIdx.x;
    const int w = t >> 6, l = t & 63;
    const int wr = w >> 1, wc = w & 1;   // 4x2 wave grid over 256x256 out
    const int ln = l & 31;   // row/col within a 32x32 sub-tile
    const int hi = l >> 5;   // k-half selector within one MFMA's K=64
    const int rowA0 = bi * 256, rowB0 = bj * 256;

    if (t < 256) lab_row[t] = labels[(rowA0 + t) >> 1];
    else lab_col[t - 256] = labels[(rowB0 + t - 256) >> 1];

    // ---- single-shot staging: wave w stages rows [w*32, w*32+32) of A and B.
    // glds s covers 4 rows (64 lanes x 16 B; row = 256 B = 16 lanes). Lane l:
    // r = w*32 + s*4 + (l>>4), slot cl = l&15, global chunk c = cl ^ (r&7).
    {
        const int rgrp = l >> 4, cl = l & 15;
        #pragma unroll
        for (int s = 0; s < 8; ++s) {
            const int r = w * 32 + s * 4 + rgrp;
            const int c = cl ^ (r & 7);
            const size_t gofs = ((size_t)r << 8) + (c << 4);
            const int lbase = (w * 32 + s * 4) * 256;  // wave-uniform
            GLDS16(efp4 + (((size_t)rowA0) << 8) + gofs, &As[lbase]);
            GLDS16(efp4 + (((size_t)rowB0) << 8) + gofs, &Bs[lbase]);
        }
    }

    // per-lane scale dwords, pre-shifted by hi*8 -> per-kk compile-time shifts.
    const int ra0 = wr * 64 + ln, ra1 = ra0 + 32;
    const int sh = hi * 8;
    unsigned dA[2][4], dB[4][4];
    {
        uint4 sa0 = *(const uint4*)(scales + (size_t)(rowA0 + ra0) * 16);
        uint4 sa1 = *(const uint4*)(scales + (size_t)(rowA0 + ra1) * 16);
        dA[0][0] = sa0.x >> sh; dA[0][1] = sa0.y >> sh;
        dA[0][2] = sa0.z >> sh; dA[0][3] = sa0.w >> sh;
        dA[1][0] = sa1.x >> sh; dA[1][1] = sa1.y >> sh;
        dA[1][2] = sa1.z >> sh; dA[1][3] = sa1.w >> sh;
        #pragma unroll
        for (int nb = 0; nb < 4; ++nb) {
            const int rb = wc * 128 + nb * 32 + ln;
            uint4 sb = *(const uint4*)(scales + (size_t)(rowB0 + rb) * 16);
            dB[nb][0] = sb.x >> sh; dB[nb][1] = sb.y >> sh;
            dB[nb][2] = sb.z >> sh; dB[nb][3] = sb.w >> sh;
        }
    }

    f32x16 acc[2][4] = {};

    __syncthreads();  // single vmcnt(0) drain: 16 glds/wave in flight

    #pragma unroll
    for (int kk = 0; kk < 8; ++kk) {
        const int q = kk * 2 + hi;          // logical 16 B chunk = 32-block id
        const int p = (q ^ (ln & 7)) << 4;  // physical byte offset in row
        const int ks = 16 * (kk & 1), kd = kk >> 1;
        union { v8i v; uint4 u[2]; } a[2], b[4];
        #pragma unroll
        for (int ma = 0; ma < 2; ++ma) {
            a[ma].u[0] = *(const uint4*)&As[(wr * 64 + ma * 32 + ln) * 256 + p];
            a[ma].u[1] = make_uint4(0, 0, 0, 0);
        }
        #pragma unroll
        for (int nb = 0; nb < 4; ++nb) {
            b[nb].u[0] = *(const uint4*)&Bs[(wc * 128 + nb * 32 + ln) * 256 + p];
            b[nb].u[1] = make_uint4(0, 0, 0, 0);
        }
        #pragma unroll
        for (int ma = 0; ma < 2; ++ma) {
            const int scA = (dA[ma][kd] >> ks) & 0xFF;
            #pragma unroll
            for (int nb = 0; nb < 4; ++nb) {
                const int scB = (dB[nb][kd] >> ks) & 0xFF;
                acc[ma][nb] = __builtin_amdgcn_mfma_scale_f32_32x32x64_f8f6f4(
                    a[ma].v, b[nb].v, acc[ma][nb], 4, 4, 0, scA, 0, scB);
            }
        }
    }

    // Epilogue: 32x32 C/D layout: col = lane&31, row = (reg&3)+8*(reg>>2)+4*(lane>>5).
    // reg outer / nb inner: each row label read ONCE per (ma,reg) -> 36 LDS
    // reads per lane instead of 256. diag is wave-uniform: off-diag blocks
    // skip the positive-pair scan entirely.
    float neg_local = 0.0f;
    const bool diag = (bi == bj);
    int labC[4];
    #pragma unroll
    for (int nb = 0; nb < 4; ++nb) labC[nb] = lab_col[wc * 128 + nb * 32 + ln];
    #pragma unroll
    for (int ma = 0; ma < 2; ++ma) {
        #pragma unroll
        for (int reg = 0; reg < 16; ++reg) {
            const int rrow = (reg & 3) + 8 * (reg >> 2) + 4 * hi;
            const int li = wr * 64 + ma * 32 + rrow;
            const int lr = lab_row[li];   // broadcast read, hoisted out of nb
            const int i = rowA0 + li;
            #pragma unroll
            for (int nb = 0; nb < 4; ++nb) {
                const int lj = wc * 128 + nb * 32 + ln;
                const int j = rowB0 + lj;
                const float S = acc[ma][nb][reg] * TEMP_INV;
                if (j > i && lr != labC[nb]) neg_local += __expf(S);
                if (diag && !(li & 1) && lj == li + 1) pvals[i >> 1] = S;
            }
        }
    }

    float s = neg_local;
    #pragma unroll
    for (int off = 32; off > 0; off >>= 1) s += __shfl_down(s, off, 64);
    if (l == 0) red[w] = s;
    __syncthreads();  // drains vmcnt(0) per wave: all pvals stores retired to L2
    if (t == 0) {
        float tot = 0.0f;
        #pragma unroll
        for (int q = 0; q < 8; ++q) tot += red[q];
        atomicAdd(ws, tot);          // device-scope neg_sum accumulate
        __threadfence();             // agent release: wb L2 (pvals + neg visible)
        const unsigned old =
            atomicAdd(((unsigned int*)ws) + 1, 1u);  // completion counter
        lastflag = (old == (unsigned)(NBLK - 1));
    }
    __syncthreads();

    // ---- last-block loss tail (replaces infonce_loss_kernel dispatch) ----
    if (lastflag) {
        __threadfence();  // agent acquire: invalidate stale L1/L2 lines
        const float neg =
            __hip_atomic_load(ws, __ATOMIC_RELAXED, __HIP_MEMORY_SCOPE_AGENT);
        float local = 0.0f;
        for (int k = t; k < NPAIRS; k += 512) {
            const float pv = __hip_atomic_load(pvals + k, __ATOMIC_RELAXED,
                                               __HIP_MEMORY_SCOPE_AGENT);
            local += logf(__expf(pv) + neg) - pv;
        }
        #pragma unroll
        for (int off = 32; off > 0; off >>= 1)
            local += __shfl_down(local, off, 64);
        if (l == 0) red[w] = local;
        __syncthreads();
        if (t == 0) {
            float tot = 0.0f;
            #pragma unroll
            for (int q = 0; q < 8; ++q) tot += red[q];
            out[0] = tot / (float)NPAIRS;
        }
    }
}

extern "C" void kernel_launch(void* const* d_in, const int* in_sizes, int n_in,
                              void* d_out, int out_size, void* d_ws, size_t ws_size,
                              hipStream_t stream) {
    const float* emb = (const float*)d_in[0];
    const int* labels = (const int*)d_in[1];
    float* out = (float*)d_out;
    float* ws = (float*)d_ws;

    const int ntot = in_sizes[0] / D;  // 4096

    infonce_norm_cast_kernel<<<ntot / 4, 256, 0, stream>>>(emb, ws, ntot);
    infonce_sim_kernel<<<NBLK, 512, 0, stream>>>(labels, ws, out);
}